// Round 7
// baseline (94.579 us; speedup 1.0000x reference)
//
#include <hip/hip_runtime.h>
#include <math.h>

#define IN_C 64
#define OUT_C 16

typedef float f4 __attribute__((ext_vector_type(4)));
typedef float f2 __attribute__((ext_vector_type(2)));

// ws layout (floats):
//   [0..63]          cst: [0]=P [1]=Q [2..17]=r_j=b1/w1 [18..33]=sp_j=0.5*w2*|w1|
//   [64 ..)          h[N][16]
//   [64+16N ..)      exn[N][16]  = exp(score(h[n][k]))
//   [64+32N ..)      sumN[N]     = sum_k exn[n][k]
// total ~13.2 MB

// ---------------------------------------------------------------------------
// Setup: fold the per-scalar MLP into 34 uniform constants.
//   score(c) = P*c + Q + sum_j sp_j * |c + r_j|
// ---------------------------------------------------------------------------
__global__ void setup_cst_kernel(const float* __restrict__ w1,
                                 const float* __restrict__ b1,
                                 const float* __restrict__ w2,
                                 const float* __restrict__ b2,
                                 float* __restrict__ cst)
{
    int j = threadIdx.x;
    if (j < 16) {
        float w = w1[j], b = b1[j], s = 0.5f * w2[j];
        cst[2 + j]  = b / w;          // r_j
        cst[18 + j] = s * fabsf(w);   // sp_j
    }
    if (j == 0) {
        float P = 0.f, Q = b2[0];
        for (int k = 0; k < 16; k++) {
            float s = 0.5f * w2[k];
            P = fmaf(w1[k], s, P);
            Q = fmaf(b1[k], s, Q);
        }
        cst[0] = P; cst[1] = Q;
    }
}

// ---------------------------------------------------------------------------
// Kernel 1: h = x @ W_lin + b_lin, PLUS per-node score-exponentials:
//   exn[n][k] = exp(score(h[n][k])), sumN[n] = sum_k exn[n][k]
// (valid because softmax is computed without max-shift; scores are O(1))
// ---------------------------------------------------------------------------
__global__ __launch_bounds__(256) void node_linear_kernel(
    const float* __restrict__ x, const float* __restrict__ W_lin,
    const float* __restrict__ b_lin, const float* __restrict__ cst,
    float* __restrict__ h, float* __restrict__ exn, float* __restrict__ sumN,
    int N)
{
    __shared__ float sW[IN_C * OUT_C];   // 4 KB
    __shared__ float sb[OUT_C];
    for (int i = threadIdx.x; i < IN_C * OUT_C; i += blockDim.x) sW[i] = W_lin[i];
    if (threadIdx.x < OUT_C) sb[threadIdx.x] = b_lin[threadIdx.x];
    __syncthreads();

    int n = blockIdx.x * blockDim.x + threadIdx.x;
    if (n >= N) return;

    float acc[OUT_C];
    #pragma unroll
    for (int j = 0; j < OUT_C; j++) acc[j] = sb[j];

    const f4* xr = (const f4*)(x + (size_t)n * IN_C);
    #pragma unroll
    for (int k4 = 0; k4 < IN_C / 4; k4++) {
        f4 xv = __builtin_nontemporal_load(xr + k4);
        #pragma unroll
        for (int kk = 0; kk < 4; kk++) {
            const float xs = xv[kk];
            const f4* wrow = (const f4*)(sW + (k4 * 4 + kk) * OUT_C);
            #pragma unroll
            for (int jq = 0; jq < 4; jq++) {
                f4 wv = wrow[jq];
                acc[jq * 4 + 0] = fmaf(xs, wv[0], acc[jq * 4 + 0]);
                acc[jq * 4 + 1] = fmaf(xs, wv[1], acc[jq * 4 + 1]);
                acc[jq * 4 + 2] = fmaf(xs, wv[2], acc[jq * 4 + 2]);
                acc[jq * 4 + 3] = fmaf(xs, wv[3], acc[jq * 4 + 3]);
            }
        }
    }

    // per-node score exps
    const float P = cst[0], Q = cst[1];
    float ex[OUT_C];
    float sum = 0.f;
    #pragma unroll
    for (int k = 0; k < OUT_C; k++) {
        const float cv = acc[k];
        float a = fmaf(P, cv, Q);
        #pragma unroll
        for (int j = 0; j < 16; j++)
            a = fmaf(fabsf(cv + cst[2 + j]), cst[18 + j], a);
        float e = __expf(a);
        ex[k] = e;
        sum += e;
    }

    f4* hr = (f4*)(h + (size_t)n * OUT_C);
    f4* xr2 = (f4*)(exn + (size_t)n * OUT_C);
    #pragma unroll
    for (int jq = 0; jq < 4; jq++) {
        f4 o, p;
        o[0] = acc[jq*4+0]; o[1] = acc[jq*4+1]; o[2] = acc[jq*4+2]; o[3] = acc[jq*4+3];
        p[0] = ex[jq*4+0];  p[1] = ex[jq*4+1];  p[2] = ex[jq*4+2];  p[3] = ex[jq*4+3];
        hr[jq] = o;
        xr2[jq] = p;
    }
    sumN[n] = sum;
}

// ---------------------------------------------------------------------------
// Kernel 2: EIGHT lanes per edge. Lane sub:
//   - owns ea columns {2sub, 2sub+1}: 16-fma transform + 2 scores (66 fma) + 2 exp
//   - nv-score exps come from the precomputed exn table (per-node reuse, E/N=10)
//   - writes out[2sub..2sub+1] and out[16+2sub..16+2sub+1] (f2 stores, coalesced)
// ---------------------------------------------------------------------------
__global__ __launch_bounds__(256) void edge_attn8_kernel(
    const float* __restrict__ edge_attr, const int* __restrict__ col,
    const float* __restrict__ W_edge, const float* __restrict__ b_edge,
    const float* __restrict__ cst, const float* __restrict__ h,
    const float* __restrict__ exn, const float* __restrict__ sumN,
    float* __restrict__ out, int E)
{
    __shared__ float sWe[8 * OUT_C];   // [d][j] row-major, 512 B
    __shared__ float sbe[OUT_C];
    if (threadIdx.x < 32)
        ((f4*)sWe)[threadIdx.x] = ((const f4*)W_edge)[threadIdx.x];
    if (threadIdx.x >= 32 && threadIdx.x < 36)
        ((f4*)sbe)[threadIdx.x - 32] = ((const f4*)b_edge)[threadIdx.x - 32];
    __syncthreads();

    const int tid = blockIdx.x * 256 + threadIdx.x;
    int e = tid >> 3;
    const bool valid = e < E;
    if (!valid) e = E - 1;                   // clamp: keep lanes defined for shuffles
    const int lane = threadIdx.x & 63;
    const int sub  = lane & 7;

    // ---- gathers (coalesced f2 per lane) ------------------------------
    const int c = col[e];
    f2 nv2 = ((const f2*)(h   + (size_t)c * OUT_C))[sub];   // nv[2sub], nv[2sub+1]
    f2 xn2 = ((const f2*)(exn + (size_t)c * OUT_C))[sub];   // exp of those scores
    const float sN = sumN[c];

    const f4* ep = (const f4*)(edge_attr + (size_t)e * 8);
    f4 eaA = ep[0], eaB = ep[1];
    float ear[8] = {eaA[0], eaA[1], eaA[2], eaA[3],
                    eaB[0], eaB[1], eaB[2], eaB[3]};

    // ---- ea columns 2sub, 2sub+1 --------------------------------------
    f2 bp = ((const f2*)sbe)[sub];
    float eax = bp[0], eay = bp[1];
    #pragma unroll
    for (int d = 0; d < 8; d++) {
        f2 w = ((const f2*)sWe)[d * 8 + sub];
        eax = fmaf(ear[d], w[0], eax);
        eay = fmaf(ear[d], w[1], eay);
    }

    // ---- 2 scores: P*c + Q + sum_j sp_j*|c + r_j|  (2 inst per j) -----
    const float P = cst[0], Q = cst[1];
    float a0 = fmaf(P, eax, Q);
    float a1 = fmaf(P, eay, Q);
    #pragma unroll
    for (int j = 0; j < 16; j++) {
        const float r  = cst[2 + j];
        const float sp = cst[18 + j];
        a0 = fmaf(fabsf(eax + r), sp, a0);
        a1 = fmaf(fabsf(eay + r), sp, a1);
    }
    const float ex0 = __expf(a0);
    const float ex1 = __expf(a1);

    // ---- softmax denominator: node part (table) + edge part (reduce) --
    float ps = ex0 + ex1;
    ps += __shfl_xor(ps, 1, 64);
    ps += __shfl_xor(ps, 2, 64);
    ps += __shfl_xor(ps, 4, 64);
    const float inv = __builtin_amdgcn_rcpf(sN + ps);

    // ---- fetch nv[sub] and nv[8+sub] from neighbor lanes --------------
    const int srcA = (lane & 56) | (sub >> 1);
    const int srcB = srcA | 4;
    float a0v = __shfl(nv2[0], srcA, 64);
    float a1v = __shfl(nv2[1], srcA, 64);
    float b0v = __shfl(nv2[0], srcB, 64);
    float b1v = __shfl(nv2[1], srcB, 64);
    const bool odd = (sub & 1);
    const float nvA = odd ? a1v : a0v;    // nv[sub]
    const float nvB = odd ? b1v : b0v;    // nv[8+sub]

    // ---- outputs ------------------------------------------------------
    if (valid) {
        const float sA = nvA * inv, sB = nvB * inv;
        f2 o01, o23;
        o01[0] = sA * xn2[0];  o01[1] = sA * xn2[1];   // out[2sub], out[2sub+1]
        o23[0] = sB * ex0;     o23[1] = sB * ex1;      // out[16+2sub], out[16+2sub+1]
        f2* op = (f2*)(out + (size_t)e * 32);
        op[sub]     = o01;                              // plain stores: L2 merges
        op[8 + sub] = o23;
    }
}

// ---------------------------------------------------------------------------
extern "C" void kernel_launch(void* const* d_in, const int* in_sizes, int n_in,
                              void* d_out, int out_size, void* d_ws, size_t ws_size,
                              hipStream_t stream) {
    const float* x         = (const float*)d_in[0];
    const float* edge_attr = (const float*)d_in[1];
    const int*   col       = (const int*)d_in[2];
    const float* W_lin     = (const float*)d_in[3];
    const float* b_lin     = (const float*)d_in[4];
    const float* W_edge    = (const float*)d_in[5];
    const float* b_edge    = (const float*)d_in[6];
    const float* w1        = (const float*)d_in[7];
    const float* b1        = (const float*)d_in[8];
    const float* w2        = (const float*)d_in[9];
    const float* b2        = (const float*)d_in[10];
    float* out = (float*)d_out;

    const int N = in_sizes[0] / IN_C;     // 100000
    const int E = in_sizes[1] / 8;        // 1000000

    float* cst  = (float*)d_ws;           // 64 floats
    float* h    = cst + 64;               // N*16
    float* exn  = h + (size_t)N * OUT_C;  // N*16
    float* sumN = exn + (size_t)N * OUT_C;// N

    setup_cst_kernel<<<1, 64, 0, stream>>>(w1, b1, w2, b2, cst);

    dim3 blk(256);
    dim3 grid1((N + 255) / 256);
    node_linear_kernel<<<grid1, blk, 0, stream>>>(x, W_lin, b_lin, cst,
                                                  h, exn, sumN, N);

    long long total = (long long)E * 8;   // 8 threads per edge
    dim3 grid2((unsigned)((total + 255) / 256));
    edge_attn8_kernel<<<grid2, blk, 0, stream>>>(edge_attr, col, W_edge, b_edge,
                                                 cst, h, exn, sumN, out, E);
}

// Round 8
// 82.044 us; speedup vs baseline: 1.1528x; 1.1528x over previous
//
#include <hip/hip_runtime.h>
#include <math.h>

#define IN_C 64
#define OUT_C 16

typedef float f4 __attribute__((ext_vector_type(4)));
typedef float f2 __attribute__((ext_vector_type(2)));

// ws layout (floats):
//   [0..63]   cst: [0]=P [1]=Q [2..17]=r_j=b1/w1 [18..33]=sp_j=0.5*w2*|w1|
//   [64..]    T[N][32] = { h[16], exn[16] }   (128 B/row, line-aligned)

// ---------------------------------------------------------------------------
// Kernel 1: h = x @ W_lin + b_lin, exn[k] = exp(score(h[k])), packed into T.
// Folded MLP: score(c) = P*c + Q + sum_j sp_j * |c + r_j|  (no max-shift
// softmax downstream; scores are O(1) so exp is safe in fp32).
// Constants computed per-thread (cheap at N=100k); block 0 publishes to ws.
// ---------------------------------------------------------------------------
__global__ __launch_bounds__(256) void node_pack_kernel(
    const float* __restrict__ x, const float* __restrict__ W_lin,
    const float* __restrict__ b_lin,
    const float* __restrict__ w1, const float* __restrict__ b1,
    const float* __restrict__ w2, const float* __restrict__ b2,
    float* __restrict__ cst, float* __restrict__ T, int N)
{
    __shared__ float sW[IN_C * OUT_C];   // 4 KB
    __shared__ float sb[OUT_C];
    for (int i = threadIdx.x; i < IN_C * OUT_C; i += blockDim.x) sW[i] = W_lin[i];
    if (threadIdx.x < OUT_C) sb[threadIdx.x] = b_lin[threadIdx.x];
    __syncthreads();

    // folded constants (uniform; ~150 VALU once per thread)
    float rj[16], spj[16];
    float P = 0.f, Q = b2[0];
    #pragma unroll
    for (int j = 0; j < 16; j++) {
        float w = w1[j], b = b1[j], s = 0.5f * w2[j];
        rj[j]  = b / w;
        spj[j] = s * fabsf(w);
        P = fmaf(w, s, P);
        Q = fmaf(b, s, Q);
    }
    if (blockIdx.x == 0 && threadIdx.x == 0) {
        cst[0] = P; cst[1] = Q;
        #pragma unroll
        for (int j = 0; j < 16; j++) {     // static indices only (no scratch)
            cst[2 + j]  = rj[j];
            cst[18 + j] = spj[j];
        }
    }

    int n = blockIdx.x * blockDim.x + threadIdx.x;
    if (n >= N) return;

    float acc[OUT_C];
    #pragma unroll
    for (int j = 0; j < OUT_C; j++) acc[j] = sb[j];

    const f4* xr = (const f4*)(x + (size_t)n * IN_C);
    #pragma unroll
    for (int k4 = 0; k4 < IN_C / 4; k4++) {
        f4 xv = __builtin_nontemporal_load(xr + k4);
        #pragma unroll
        for (int kk = 0; kk < 4; kk++) {
            const float xs = xv[kk];
            const f4* wrow = (const f4*)(sW + (k4 * 4 + kk) * OUT_C);
            #pragma unroll
            for (int jq = 0; jq < 4; jq++) {
                f4 wv = wrow[jq];
                acc[jq * 4 + 0] = fmaf(xs, wv[0], acc[jq * 4 + 0]);
                acc[jq * 4 + 1] = fmaf(xs, wv[1], acc[jq * 4 + 1]);
                acc[jq * 4 + 2] = fmaf(xs, wv[2], acc[jq * 4 + 2]);
                acc[jq * 4 + 3] = fmaf(xs, wv[3], acc[jq * 4 + 3]);
            }
        }
    }

    // per-node score exps
    float ex[OUT_C];
    #pragma unroll
    for (int k = 0; k < OUT_C; k++) {
        const float cv = acc[k];
        float a = fmaf(P, cv, Q);
        #pragma unroll
        for (int j = 0; j < 16; j++)
            a = fmaf(fabsf(cv + rj[j]), spj[j], a);
        ex[k] = __expf(a);
    }

    // packed 128 B row: [h(16) | exn(16)]
    f4* Tp = (f4*)(T + (size_t)n * 32);
    #pragma unroll
    for (int jq = 0; jq < 4; jq++) {
        f4 o, p;
        o[0] = acc[jq*4+0]; o[1] = acc[jq*4+1]; o[2] = acc[jq*4+2]; o[3] = acc[jq*4+3];
        p[0] = ex[jq*4+0];  p[1] = ex[jq*4+1];  p[2] = ex[jq*4+2];  p[3] = ex[jq*4+3];
        Tp[jq]     = o;
        Tp[4 + jq] = p;
    }
}

// ---------------------------------------------------------------------------
// Kernel 2: EIGHT lanes per edge, ONE random line per edge.
// Lane sub loads T quad (sub<4: nv[4sub..], sub>=4: exn[4(sub-4)..]),
// computes ea columns {2sub,2sub+1} -> 2 scores -> 2 exps,
// reduces the denominator (node part from lanes 4..7's quads, edge part from
// everyone) in one 3-step shfl_xor tree, redistributes via 12 shuffles, and
// writes one f4 (wave-contiguous 1 KB store).
// ---------------------------------------------------------------------------
__global__ __launch_bounds__(256) void edge_attn8_kernel(
    const float* __restrict__ edge_attr, const int* __restrict__ col,
    const float* __restrict__ W_edge, const float* __restrict__ b_edge,
    const float* __restrict__ cst, const float* __restrict__ T,
    float* __restrict__ out, int E)
{
    __shared__ float sWe[8 * OUT_C];   // [d][j] row-major, 512 B
    __shared__ float sbe[OUT_C];
    if (threadIdx.x < 32)
        ((f4*)sWe)[threadIdx.x] = ((const f4*)W_edge)[threadIdx.x];
    if (threadIdx.x < 4)
        ((f4*)sbe)[threadIdx.x] = ((const f4*)b_edge)[threadIdx.x];
    __syncthreads();

    const int tid = blockIdx.x * 256 + threadIdx.x;
    int e = tid >> 3;
    const bool valid = e < E;
    if (!valid) e = E - 1;
    const int lane = threadIdx.x & 63;
    const int sub  = lane & 7;
    const int base = lane & 56;

    // ---- memory: 1 random line + coalesced streams --------------------
    const int c = col[e];
    f4 t = ((const f4*)(T + (size_t)c * 32))[sub];          // ONE line/edge

    const f4* ep = (const f4*)(edge_attr + (size_t)e * 8);
    f4 eaA = ep[0], eaB = ep[1];
    float ear[8] = {eaA[0], eaA[1], eaA[2], eaA[3],
                    eaB[0], eaB[1], eaB[2], eaB[3]};

    // ---- ea columns 2sub, 2sub+1 --------------------------------------
    f2 bp = ((const f2*)sbe)[sub];
    float eax = bp[0], eay = bp[1];
    #pragma unroll
    for (int d = 0; d < 8; d++) {
        f2 w = ((const f2*)sWe)[d * 8 + sub];
        eax = fmaf(ear[d], w[0], eax);
        eay = fmaf(ear[d], w[1], eay);
    }

    // ---- 2 scores -> exps (uniform consts are SGPR s_loads) -----------
    const float P = cst[0], Q = cst[1];
    float a0 = fmaf(P, eax, Q);
    float a1 = fmaf(P, eay, Q);
    #pragma unroll
    for (int j = 0; j < 16; j++) {
        const float r  = cst[2 + j];
        const float sp = cst[18 + j];
        a0 = fmaf(fabsf(eax + r), sp, a0);
        a1 = fmaf(fabsf(eay + r), sp, a1);
    }
    const float ex0 = __expf(a0);
    const float ex1 = __expf(a1);

    // ---- denominator: node exps live in lanes 4..7's quads ------------
    const float tq = (t[0] + t[1]) + (t[2] + t[3]);
    float ps = ex0 + ex1 + ((sub >= 4) ? tq : 0.f);
    ps += __shfl_xor(ps, 1, 64);
    ps += __shfl_xor(ps, 2, 64);
    ps += __shfl_xor(ps, 4, 64);
    const float inv = __builtin_amdgcn_rcpf(ps);

    // ---- redistribute: nv pair, exn quad, edge-exp quad ---------------
    const int srcNV = base | (sub >> 1);             // lane with nv[4*(sub>>1)..]
    float n0 = __shfl(t[0], srcNV, 64), n1 = __shfl(t[1], srcNV, 64);
    float n2 = __shfl(t[2], srcNV, 64), n3 = __shfl(t[3], srcNV, 64);
    const bool hi = (sub & 1);
    const float nvA = hi ? n2 : n0;                  // nv[2sub]
    const float nvB = hi ? n3 : n1;                  // nv[2sub+1]

    const int srcEX = base | (sub & 3) | 4;          // lane with exn[4(sub&3)..]
    float q0 = __shfl(t[0], srcEX, 64), q1 = __shfl(t[1], srcEX, 64);
    float q2 = __shfl(t[2], srcEX, 64), q3 = __shfl(t[3], srcEX, 64);

    const int s2 = (sub & 3) * 2;                    // edge-exp sources
    const int srcE0 = base | s2, srcE1 = base | (s2 + 1);
    float g0 = __shfl(ex0, srcE0, 64), g1 = __shfl(ex1, srcE0, 64);
    float g2 = __shfl(ex0, srcE1, 64), g3 = __shfl(ex1, srcE1, 64);

    const bool lo = (sub < 4);
    const float m0 = lo ? q0 : g0, m1 = lo ? q1 : g1;
    const float m2 = lo ? q2 : g2, m3 = lo ? q3 : g3;

    // ---- out[e][4sub + 0..3] = nv[(4sub+t)>>1] * attn ------------------
    if (valid) {
        const float sA = nvA * inv, sB = nvB * inv;
        f4 o;
        o[0] = sA * m0; o[1] = sA * m1;
        o[2] = sB * m2; o[3] = sB * m3;
        ((f4*)(out + (size_t)e * 32))[sub] = o;      // 1 KB contiguous / wave
    }
}

// ---------------------------------------------------------------------------
extern "C" void kernel_launch(void* const* d_in, const int* in_sizes, int n_in,
                              void* d_out, int out_size, void* d_ws, size_t ws_size,
                              hipStream_t stream) {
    const float* x         = (const float*)d_in[0];
    const float* edge_attr = (const float*)d_in[1];
    const int*   col       = (const int*)d_in[2];
    const float* W_lin     = (const float*)d_in[3];
    const float* b_lin     = (const float*)d_in[4];
    const float* W_edge    = (const float*)d_in[5];
    const float* b_edge    = (const float*)d_in[6];
    const float* w1        = (const float*)d_in[7];
    const float* b1        = (const float*)d_in[8];
    const float* w2        = (const float*)d_in[9];
    const float* b2        = (const float*)d_in[10];
    float* out = (float*)d_out;

    const int N = in_sizes[0] / IN_C;     // 100000
    const int E = in_sizes[1] / 8;        // 1000000

    float* cst = (float*)d_ws;            // 64 floats (keeps T 256B-aligned)
    float* T   = cst + 64;                // N*32 floats = 12.8 MB

    dim3 blk(256);
    dim3 grid1((N + 255) / 256);
    node_pack_kernel<<<grid1, blk, 0, stream>>>(x, W_lin, b_lin,
                                                w1, b1, w2, b2, cst, T, N);

    long long total = (long long)E * 8;   // 8 threads per edge
    dim3 grid2((unsigned)((total + 255) / 256));
    edge_attn8_kernel<<<grid2, blk, 0, stream>>>(edge_attr, col, W_edge, b_edge,
                                                 cst, T, out, E);
}